// Round 9
// baseline (95.655 us; speedup 1.0000x reference)
//
#include <hip/hip_runtime.h>

// Problem constants: input [8,16,512,1024] f32, disp [8,1,512,1024] f32
constexpr int B = 8;
constexpr int C = 16;
constexpr int H = 512;
constexpr int W = 1024;
constexpr int WAVES = 8;              // waves per block = channels per block
constexpr int THREADS = WAVES * 64;   // 512
constexpr int CPB = WAVES;            // 8 channels per block, 2 blocks per (b,h)

// Barrier-free design: each wave owns ONE (b,h,c) channel row end-to-end.
// It async-stages its 4 KB row into its private LDS slice via
// global_load_lds (linear dest = wave-uniform base + lane*16B), issues its
// 16 disp loads, does ONE per-wave s_waitcnt vmcnt(0), then gathers+stores.
// No __syncthreads anywhere -> every wave on the CU is an independent
// pipeline; no block-wide stage->barrier->gather serialization.
//
// Math (identical to reference):
//   x  = clip(w + disp, 0, W-1); x0 = floor(x); x1 = min(x0+1, W-1)
//   wl = x1 - x; wr = x - x0  (both exactly 0 when x0 == W-1, so gathering
//   from a = min(x0, W-2), a+1 is always correct and always in-bounds)
__global__ __launch_bounds__(THREADS) void warp_wave_row(
    const float* __restrict__ input,
    const float* __restrict__ disp,
    float* __restrict__ out)
{
    __shared__ float lds[CPB * W];     // 8 * 4 KiB = 32 KiB

    const int blk = blockIdx.x;
    const int bh  = blk >> 1;          // b*H + h
    const int cg  = blk & 1;           // channel group (0: c0-7, 1: c8-15)
    const int b   = bh >> 9;           // H = 512
    const int h   = bh & (H - 1);

    const int wid  = threadIdx.x >> 6;
    const int lane = threadIdx.x & 63;
    const int c    = cg * CPB + wid;

    const float* __restrict__ row_in  = input + ((b * C + c) * H + h) * W;
    float* __restrict__       row_out = out   + ((b * C + c) * H + h) * W;
    const float* __restrict__ row_d   = disp  + bh * W;

    float* lds_row = &lds[wid * W];    // this wave's private 4 KB slice

    // ---- Per-wave async stage: 1024 floats = 4 iters x 64 lanes x 16 B ----
    // LDS dest is wave-uniform (lds_row + i*256); HW adds lane*16.
    // Global src is per-lane: row_in + (i*64 + lane) float4s. Linear==linear.
#pragma unroll
    for (int i = 0; i < 4; ++i) {
        __builtin_amdgcn_global_load_lds(
            (const __attribute__((address_space(1))) void*)(row_in + (i * 64 + lane) * 4),
            (__attribute__((address_space(3))) void*)(lds_row + i * 256),
            16, 0, 0);
    }

    // ---- Issue all 16 disp loads while staging is in flight ----
    float dv[16];
#pragma unroll
    for (int j = 0; j < 16; ++j)
        dv[j] = row_d[j * 64 + lane];

    // One per-wave drain: staging DMA + disp loads all complete.
    // ds_reads below are memory ops, so the "memory" clobber orders them.
    asm volatile("s_waitcnt vmcnt(0)" ::: "memory");

    // ---- 16 positions per lane, p = j*64 + lane (coalesced stores) ----
#pragma unroll
    for (int j = 0; j < 16; ++j) {
        const int p = j * 64 + lane;
        float x = fminf(fmaxf((float)p + dv[j], 0.0f), (float)(W - 1));
        const int   ix  = (int)x;          // == floor(x) since x >= 0
        const float x0f = (float)ix;
        const float wr  = x - x0f;
        const float wl  = fminf(x0f + 1.0f, (float)(W - 1)) - x;
        const int   a   = min(ix, W - 2);
        const float L = lds_row[a];
        const float R = lds_row[a + 1];
        __builtin_nontemporal_store(wl * L + wr * R, row_out + p);
    }
}

extern "C" void kernel_launch(void* const* d_in, const int* in_sizes, int n_in,
                              void* d_out, int out_size, void* d_ws, size_t ws_size,
                              hipStream_t stream) {
    const float* input = (const float*)d_in[0];
    const float* disp  = (const float*)d_in[1];
    float* out = (float*)d_out;

    const int grid = B * H * 2;   // 8192 blocks: (b,h) x channel-group
    warp_wave_row<<<grid, THREADS, 0, stream>>>(input, disp, out);
}

// Round 10
// 90.741 us; speedup vs baseline: 1.0542x; 1.0542x over previous
//
#include <hip/hip_runtime.h>

// Problem constants: input [8,16,512,1024] f32, disp [8,1,512,1024] f32
constexpr int B = 8;
constexpr int C = 16;
constexpr int H = 512;
constexpr int W = 1024;
constexpr int CPB = 4;               // channels per work item
constexpr int NCG = C / CPB;         // 4 channel-groups per (b,h)
constexpr int THREADS = 256;         // 4 waves; wave w stages channel w
constexpr int NITEMS = B * H * NCG;  // 16384 work items

// Persistent double-buffered pipeline (T3/T4-lite):
//   iter k: issue global_load_lds for item k+1 -> buf[(k+1)&1]  (4/wave)
//           + prefetch disp row k+1 -> regs (4 loads)
//           s_waitcnt vmcnt(24)   <- retires item-k's 8 loads exactly
//                                    (newer: 16 stores of k-1 + 8 new loads);
//                                    NEVER drains to 0 in the loop
//           s_barrier             <- all waves' item-k DMA now visible
//           gather item k from buf[k&1] (weights shared across 4 channels),
//           16 nontemporal stores
//           s_barrier             <- buf[k&1] free for iter k+1's DMA
// Math identical to reference:
//   x = clip(w+disp, 0, W-1); x0 = floor(x); x1 = min(x0+1, W-1)
//   wl = x1-x; wr = x-x0  (both exactly 0 when x0==W-1, so gathering from
//   a = min(x0, W-2), a+1 is always correct and always in-bounds)
__global__ __launch_bounds__(THREADS) void warp_pipe(
    const float* __restrict__ input,
    const float* __restrict__ disp,
    float* __restrict__ out)
{
    __shared__ float buf[2][CPB][W];   // 2 x 16 KiB = 32 KiB

    const int t    = threadIdx.x;
    const int wid  = t >> 6;
    const int lane = t & 63;

    // chunked persistent distribution: block gets [g0, g0+n)
    const int nblk = gridDim.x;
    const int npb  = NITEMS / nblk;
    const int rem  = NITEMS - npb * nblk;
    const int bid  = blockIdx.x;
    const int g0   = bid * npb + (bid < rem ? bid : rem);
    const int n    = npb + (bid < rem ? 1 : 0);
    if (n <= 0) return;

    // item g -> (b, cg, h); consecutive g share a disp row (L1/L2 hits)
    auto stage_item = [&](int slot, int g) {
        const int bh = g >> 2, cgi = g & 3;
        const float* src = input +
            ((((bh >> 9) * C) + cgi * CPB + wid) * H + (bh & (H - 1))) * W;
#pragma unroll
        for (int i = 0; i < 4; ++i)
            __builtin_amdgcn_global_load_lds(
                (const __attribute__((address_space(1))) void*)(src + i * 256 + lane * 4),
                (__attribute__((address_space(3))) void*)(&buf[slot][wid][i * 256]),
                16, 0, 0);
    };

    auto load_disp = [&](int g, float* dv) {
        const float* dsrc = disp + (g >> 2) * W;   // (b*H+h)*W == bh*W
#pragma unroll
        for (int j = 0; j < 4; ++j) dv[j] = dsrc[j * 256 + t];
    };

    auto gather_item = [&](int slot, int g, const float* dv) {
        const int bh = g >> 2, cgi = g & 3;
        const int bb = bh >> 9, hh = bh & (H - 1);
        float wl[4], wr[4];
        int   a[4];
#pragma unroll
        for (int j = 0; j < 4; ++j) {
            float x = fminf(fmaxf((float)(j * 256 + t) + dv[j], 0.0f), (float)(W - 1));
            const int   ix  = (int)x;              // == floor(x), x >= 0
            const float x0f = (float)ix;
            wr[j] = x - x0f;
            wl[j] = fminf(x0f + 1.0f, (float)(W - 1)) - x;
            a[j]  = min(ix, W - 2);
        }
#pragma unroll
        for (int ch = 0; ch < CPB; ++ch) {
            const float* __restrict__ row = &buf[slot][ch][0];
            float* __restrict__ orow = out +
                (((bb * C) + cgi * CPB + ch) * H + hh) * W;
#pragma unroll
            for (int j = 0; j < 4; ++j) {
                const float L = row[a[j]];
                const float R = row[a[j] + 1];
                __builtin_nontemporal_store(wl[j] * L + wr[j] * R,
                                            orow + j * 256 + t);
            }
        }
    };

    float dv[4], dn[4];

    // prologue: item 0 in flight
    stage_item(0, g0);
    load_disp(g0, dv);

    if (n == 1) {
        asm volatile("s_waitcnt vmcnt(0)" ::: "memory");
        __builtin_amdgcn_s_barrier();
        asm volatile("" ::: "memory");
        gather_item(0, g0, dv);
        return;
    }

    // iter 0 (peeled): only item-1's 8 loads are newer than item-0's
    stage_item(1, g0 + 1);
    load_disp(g0 + 1, dn);
    asm volatile("s_waitcnt vmcnt(8)" ::: "memory");
    __builtin_amdgcn_s_barrier();
    asm volatile("" ::: "memory");
    gather_item(0, g0, dv);
#pragma unroll
    for (int j = 0; j < 4; ++j) dv[j] = dn[j];
    asm volatile("" ::: "memory");
    __builtin_amdgcn_s_barrier();
    asm volatile("" ::: "memory");

    // steady state: 16 stores(k-1) + 8 loads(k+1) newer than item-k's loads
    for (int k = 1; k < n - 1; ++k) {
        stage_item((k + 1) & 1, g0 + k + 1);
        load_disp(g0 + k + 1, dn);
        asm volatile("s_waitcnt vmcnt(24)" ::: "memory");
        __builtin_amdgcn_s_barrier();
        asm volatile("" ::: "memory");
        gather_item(k & 1, g0 + k, dv);
#pragma unroll
        for (int j = 0; j < 4; ++j) dv[j] = dn[j];
        asm volatile("" ::: "memory");
        __builtin_amdgcn_s_barrier();
        asm volatile("" ::: "memory");
    }

    // last item: only the 16 stores of iter n-2 are newer than its loads
    asm volatile("s_waitcnt vmcnt(16)" ::: "memory");
    __builtin_amdgcn_s_barrier();
    asm volatile("" ::: "memory");
    gather_item((n - 1) & 1, g0 + n - 1, dv);
}

extern "C" void kernel_launch(void* const* d_in, const int* in_sizes, int n_in,
                              void* d_out, int out_size, void* d_ws, size_t ws_size,
                              hipStream_t stream) {
    const float* input = (const float*)d_in[0];
    const float* disp  = (const float*)d_in[1];
    float* out = (float*)d_out;

    // size the persistent grid to exactly fill the chip (no tail imbalance)
    int nb = 0;
    if (hipOccupancyMaxActiveBlocksPerMultiprocessor(&nb, warp_pipe, THREADS, 0)
            != hipSuccess || nb < 1)
        nb = 4;                        // safe fallback: 4 x 32 KiB = 128 KiB LDS
    if (nb > 8) nb = 8;
    int grid = nb * 256;               // 256 CUs
    if (grid > NITEMS) grid = NITEMS;

    warp_pipe<<<grid, THREADS, 0, stream>>>(input, disp, out);
}

// Round 11
// 89.624 us; speedup vs baseline: 1.0673x; 1.0125x over previous
//
#include <hip/hip_runtime.h>

// Problem constants: input [8,16,512,1024] f32, disp [8,1,512,1024] f32
constexpr int B = 8;
constexpr int C = 16;
constexpr int H = 512;
constexpr int W = 1024;
constexpr int HW = H * W;
constexpr int CPB = 4;                 // channels per block
constexpr int NCG = C / CPB;           // 4 channel-groups per (b,h)
constexpr int THREADS = 256;           // 4 waves; wave w stages channel w
constexpr int NBLK = B * H * NCG;      // 16384 blocks
constexpr int NPX = NBLK / 8;          // 2048 blocks per XCD chunk

// R8 structure pushed to its occupancy limit: one-shot blocks, ONE barrier,
// CPB=4 channels in 16 KB LDS, 256 threads -> 8 blocks/CU = 8 independent
// barrier domains at the full 32 waves/CU (R8 had 4 domains; R6->R7->R8
// showed monotone gains from more domains). Staging uses global_load_lds
// (no VGPR round-trip; linear dest = wave-uniform base + lane*16 B).
// XCD-chunked swizzle: the 4 cg-blocks of one (b,h) — which share a disp
// row — plus neighboring h rows land on the same XCD's L2 (T1).
//
// Math identical to reference:
//   x = clip(w+disp, 0, W-1); x0 = floor(x); x1 = min(x0+1, W-1)
//   wl = x1-x; wr = x-x0  (both exactly 0 when x0==W-1, so gathering from
//   a = min(x0, W-2) and a+1 is always correct and always in-bounds)
__global__ __launch_bounds__(THREADS, 8) void warp_lds8(
    const float* __restrict__ input,
    const float* __restrict__ disp,
    float* __restrict__ out)
{
    __shared__ float lds[CPB][W];      // 16 KiB

    // bijective XCD-chunk swizzle: HW round-robins bid across 8 XCDs;
    // give XCD k the contiguous logical range [k*2048, (k+1)*2048).
    const int bid = blockIdx.x;
    const int g   = (bid & 7) * NPX + (bid >> 3);

    const int bh = g >> 2;             // b*H + h
    const int cg = g & 3;              // channel group
    const int b  = bh >> 9;            // H = 512
    const int h  = bh & (H - 1);
    const int t  = threadIdx.x;
    const int wid  = t >> 6;
    const int lane = t & 63;

    const int base0 = ((b * C) + cg * CPB) * HW + h * W;  // (b, cg*4, h, 0)

    // ---- Stage: wave `wid` DMAs channel `wid`'s row (1024 floats) ----
    // dest wave-uniform + lane*16B (HW); src per-lane. Linear == linear.
    const float* src = input + base0 + wid * HW;
#pragma unroll
    for (int i = 0; i < 4; ++i)
        __builtin_amdgcn_global_load_lds(
            (const __attribute__((address_space(1))) void*)(src + i * 256 + lane * 4),
            (__attribute__((address_space(3))) void*)(&lds[wid][i * 256]),
            16, 0, 0);

    // ---- Weights for this thread's 4 positions (overlaps DMA latency) ----
    const float* drow = disp + bh * W;
    float wl[4], wr[4];
    int   a[4];
#pragma unroll
    for (int j = 0; j < 4; ++j) {
        const int p = j * 256 + t;
        float x = fminf(fmaxf((float)p + drow[p], 0.0f), (float)(W - 1));
        const int   ix  = (int)x;          // == floor(x) since x >= 0
        const float x0f = (float)ix;
        wr[j] = x - x0f;
        wl[j] = fminf(x0f + 1.0f, (float)(W - 1)) - x;
        a[j]  = min(ix, W - 2);
    }

    __syncthreads();   // drains the global_load_lds DMA (vmcnt) + publishes LDS

    // ---- Gather from LDS (stride-1/lane: 2 lanes/bank = free), store ----
#pragma unroll
    for (int ch = 0; ch < CPB; ++ch) {
        const float* __restrict__ row = &lds[ch][0];
        float* __restrict__ orow = out + base0 + ch * HW;
#pragma unroll
        for (int j = 0; j < 4; ++j) {
            const float L = row[a[j]];
            const float R = row[a[j] + 1];
            __builtin_nontemporal_store(wl[j] * L + wr[j] * R,
                                        orow + j * 256 + t);
        }
    }
}

extern "C" void kernel_launch(void* const* d_in, const int* in_sizes, int n_in,
                              void* d_out, int out_size, void* d_ws, size_t ws_size,
                              hipStream_t stream) {
    const float* input = (const float*)d_in[0];
    const float* disp  = (const float*)d_in[1];
    float* out = (float*)d_out;

    warp_lds8<<<NBLK, THREADS, 0, stream>>>(input, disp, out);
}

// Round 12
// 86.218 us; speedup vs baseline: 1.1095x; 1.0395x over previous
//
#include <hip/hip_runtime.h>

// Problem constants: input [8,16,512,1024] f32, disp [8,1,512,1024] f32
constexpr int B = 8;
constexpr int C = 16;
constexpr int H = 512;
constexpr int W = 1024;
constexpr int HW = H * W;
constexpr int CPB = 8;               // channels per block (R8 geometry)
constexpr int THREADS = 512;         // 8 waves
constexpr int NBLK = B * H * 2;      // 8192 one-shot blocks, no swizzle

// R8 geometry (CPB=8, 512 thr, 32 KB LDS, 4 blocks/CU) with ONE structural
// change: the stage is split into two 4-row DMA halves with counted vmcnt
// waits, so the gather of rows 0-3 overlaps the inbound DMA of rows 4-7.
// Per-wave vmem issue order (all pure vmcnt, thanks to global_load_lds):
//   2 disp loads | 2 gload_lds (rows 0-3) | 2 gload_lds (rows 4-7)
//   [compiler vmcnt for dv use retires disp]       weights compute
//   vmcnt(2)  -> half-0 in LDS          s_barrier -> visible to all waves
//   gather rows 0-3, 8 nt stores        (half-1 DMA still in flight)
//   vmcnt(8)  -> half-1 in LDS (in-order counter: 2 oldest = half-1 loads;
//                up to 8 newer stores may remain outstanding)
//   s_barrier -> visible; gather rows 4-7, 8 nt stores
// Math identical to reference:
//   x = clip(w+disp, 0, W-1); x0 = floor(x); x1 = min(x0+1, W-1)
//   wl = x1-x; wr = x-x0  (both exactly 0 when x0==W-1, so gathering from
//   a = min(x0, W-2) and a+1 is always correct and always in-bounds)
__global__ __launch_bounds__(THREADS) void warp_halfpipe(
    const float* __restrict__ input,
    const float* __restrict__ disp,
    float* __restrict__ out)
{
    __shared__ float lds[CPB][W];    // 32 KiB

    const int g  = blockIdx.x;
    const int bh = g >> 1;           // b*H + h
    const int cg = g & 1;            // channel group (0: c0-7, 1: c8-15)
    const int b  = bh >> 9;          // H = 512
    const int h  = bh & (H - 1);
    const int t  = threadIdx.x;
    const int wid  = t >> 6;
    const int lane = t & 63;

    const int base0 = ((b * C) + cg * CPB) * HW + h * W;  // (b, cg*8, h, 0)

    // ---- 1) disp loads first (oldest in vmcnt queue) ----
    const float* drow = disp + bh * W;
    const float d0 = drow[t];
    const float d1 = drow[512 + t];

    // ---- 2) DMA half-0 (rows 0-3): 1024 float4 = 2 iters x 8 waves x 64 ----
    // chunk = i*512 + wid*64 (+lane); row c = chunk>>8 is wave-uniform, and
    // the 64-lane span never crosses a 256-float4 row boundary.
#pragma unroll
    for (int i = 0; i < 2; ++i) {
        const int fb = i * 512 + wid * 64;       // base float4 index [0,1024)
        const int c  = fb >> 8;
        const int q  = (fb & 255) << 2;          // float offset in row
        __builtin_amdgcn_global_load_lds(
            (const __attribute__((address_space(1))) void*)
                (input + base0 + c * HW + q + lane * 4),
            (__attribute__((address_space(3))) void*)(&lds[c][q]),
            16, 0, 0);
    }
    // ---- 3) DMA half-1 (rows 4-7) ----
#pragma unroll
    for (int i = 0; i < 2; ++i) {
        const int fb = 1024 + i * 512 + wid * 64;
        const int c  = fb >> 8;
        const int q  = (fb & 255) << 2;
        __builtin_amdgcn_global_load_lds(
            (const __attribute__((address_space(1))) void*)
                (input + base0 + c * HW + q + lane * 4),
            (__attribute__((address_space(3))) void*)(&lds[c][q]),
            16, 0, 0);
    }

    // ---- 4) weights for p0 = t, p1 = t+512 (compiler waits disp only) ----
    float x   = fminf(fmaxf((float)t + d0, 0.0f), (float)(W - 1));
    int   ix  = (int)x;
    float x0f = (float)ix;
    const float wr0 = x - x0f;
    const float wl0 = fminf(x0f + 1.0f, (float)(W - 1)) - x;
    const int   a0  = min(ix, W - 2);

    x   = fminf(fmaxf((float)(512 + t) + d1, 0.0f), (float)(W - 1));
    ix  = (int)x;
    x0f = (float)ix;
    const float wr1 = x - x0f;
    const float wl1 = fminf(x0f + 1.0f, (float)(W - 1)) - x;
    const int   a1  = min(ix, W - 2);

    // ---- 5) half-0 ready -> barrier -> gather rows 0-3 ----
    asm volatile("s_waitcnt vmcnt(2)" ::: "memory");   // half-1 stays in flight
    __builtin_amdgcn_s_barrier();
    asm volatile("" ::: "memory");
#pragma unroll
    for (int ch = 0; ch < 4; ++ch) {
        const float* __restrict__ row = &lds[ch][0];
        float* __restrict__ orow = out + base0 + ch * HW;
        __builtin_nontemporal_store(wl0 * row[a0] + wr0 * row[a0 + 1], orow + t);
        __builtin_nontemporal_store(wl1 * row[a1] + wr1 * row[a1 + 1], orow + 512 + t);
    }

    // ---- 6) half-1 ready (8 newer stores may remain) -> gather rows 4-7 ----
    asm volatile("s_waitcnt vmcnt(8)" ::: "memory");
    __builtin_amdgcn_s_barrier();
    asm volatile("" ::: "memory");
#pragma unroll
    for (int ch = 4; ch < 8; ++ch) {
        const float* __restrict__ row = &lds[ch][0];
        float* __restrict__ orow = out + base0 + ch * HW;
        __builtin_nontemporal_store(wl0 * row[a0] + wr0 * row[a0 + 1], orow + t);
        __builtin_nontemporal_store(wl1 * row[a1] + wr1 * row[a1 + 1], orow + 512 + t);
    }
}

extern "C" void kernel_launch(void* const* d_in, const int* in_sizes, int n_in,
                              void* d_out, int out_size, void* d_ws, size_t ws_size,
                              hipStream_t stream) {
    const float* input = (const float*)d_in[0];
    const float* disp  = (const float*)d_in[1];
    float* out = (float*)d_out;

    warp_halfpipe<<<NBLK, THREADS, 0, stream>>>(input, disp, out);
}